// Round 5
// baseline (237.599 us; speedup 1.0000x reference)
//
#include <hip/hip_runtime.h>
#include <math.h>

// predicted/target: (B,T,H,W,1) fp32
#define BB 8
#define TT 16
#define HH 256
#define WW 256
#define NPX (TT * HH * WW)      // 1,048,576 px per sample
#define CROWS 16                // output rows per ssim block
#define NSTEP (CROWS + 10)      // staged rows per block = 26
#define NBLK (BB * TT * (HH / CROWS)) // 2048 ssim blocks

// ws float layout (per-block partials from k_reduce; 512 = 8 samples x 64 chunks)
#define P_MINP 0
#define P_MAXP 512
#define P_MINT 1024
#define P_MAXT 1536
#define P_SUMT 2048
#define WS_S   2560   // accumulated valid-weighted ssim sum
#define WS_CNT 2561   // done-block counter (uint)

typedef float v2f __attribute__((ext_vector_type(2)));

// Gaussian taps (exp(-(i-5)^2/4.5), normalized) as literals.
#define G0 0.0010283776f
#define G1 0.0075987582f
#define G2 0.0360008014f
#define G3 0.1093606427f
#define G4 0.2130055745f
#define G5 0.2660117857f
#define GA_(k) ((k) == 0 || (k) == 10 ? G0 : (k) == 1 || (k) == 9 ? G1 \
              : (k) == 2 || (k) == 8 ? G2 : (k) == 3 || (k) == 7 ? G3 \
              : (k) == 4 || (k) == 6 ? G4 : G5)

// Per-sample min/max of pred & targ + sum(targ), one partial per block.
__global__ __launch_bounds__(256) void k_reduce(const float* __restrict__ p,
                                                const float* __restrict__ t,
                                                float* __restrict__ wsf) {
  const int b = blockIdx.x >> 6;
  const size_t base = (size_t)b * NPX + (size_t)(blockIdx.x & 63) * (NPX / 64);
  const int tid = threadIdx.x;

  float mnp = 3.4e38f, mxp = -3.4e38f, mnt = 3.4e38f, mxt = -3.4e38f, st = 0.f;
  const float4* p4 = (const float4*)(p + base);
  const float4* t4 = (const float4*)(t + base);
#pragma unroll 4
  for (int it = 0; it < 16; ++it) {
    float4 a = p4[it * 256 + tid];
    float4 c = t4[it * 256 + tid];
    mnp = fminf(mnp, fminf(fminf(a.x, a.y), fminf(a.z, a.w)));
    mxp = fmaxf(mxp, fmaxf(fmaxf(a.x, a.y), fmaxf(a.z, a.w)));
    mnt = fminf(mnt, fminf(fminf(c.x, c.y), fminf(c.z, c.w)));
    mxt = fmaxf(mxt, fmaxf(fmaxf(c.x, c.y), fmaxf(c.z, c.w)));
    st += c.x + c.y + c.z + c.w;
  }
  for (int off = 32; off > 0; off >>= 1) {
    mnp = fminf(mnp, __shfl_down(mnp, off));
    mxp = fmaxf(mxp, __shfl_down(mxp, off));
    mnt = fminf(mnt, __shfl_down(mnt, off));
    mxt = fmaxf(mxt, __shfl_down(mxt, off));
    st += __shfl_down(st, off);
  }
  __shared__ float s_mnp[4], s_mxp[4], s_mnt[4], s_mxt[4], s_st[4];
  int wave = tid >> 6, lane = tid & 63;
  if (lane == 0) {
    s_mnp[wave] = mnp; s_mxp[wave] = mxp;
    s_mnt[wave] = mnt; s_mxt[wave] = mxt; s_st[wave] = st;
  }
  __syncthreads();
  if (tid == 0) {
    for (int w = 1; w < 4; ++w) {
      mnp = fminf(mnp, s_mnp[w]); mxp = fmaxf(mxp, s_mxp[w]);
      mnt = fminf(mnt, s_mnt[w]); mxt = fmaxf(mxt, s_mxt[w]);
      st += s_st[w];
    }
    wsf[P_MINP + blockIdx.x] = mnp;
    wsf[P_MAXP + blockIdx.x] = mxp;
    wsf[P_MINT + blockIdx.x] = mnt;
    wsf[P_MAXT + blockIdx.x] = mxt;
    wsf[P_SUMT + blockIdx.x] = st;
    if (blockIdx.x == 0) {
      wsf[WS_S] = 0.f;
      ((unsigned*)wsf)[WS_CNT] = 0u;
    }
  }
}

// One row-step of the fused separable SSIM pipeline. jj literal -> buffer
// parity, ring slot, output guard all compile-time; ring arrays see only
// constant indices -> stay in VGPRs (r4: VGPR=48, zero scratch).
// sched_barrier(0x7): ALU may cross step boundaries (ILP), memory ops may
// not (prevents the r3 load-hoisting register blowup).
#define STEP(J) do {                                                         \
    constexpr int jj = (J);                                                  \
    constexpr int buf = jj & 1;                                              \
    constexpr int slot = jj % 11;                                            \
    const bool in = (unsigned)(ystart + jj) < (unsigned)HH;                  \
    v2f nv;                                                                  \
    nv.x = in ? fmaf(tcur, ts, tb) : 0.f;                                    \
    nv.y = in ? fmaf(pcur, ps, pb) : 0.f;                                    \
    srow[buf][x + 5] = nv;                                                   \
    if constexpr (jj < NSTEP - 1) {                                          \
      const int yn = min(max(ystart + jj + 1, 0), HH - 1);                   \
      tnxt = tptr[(size_t)yn * WW + x];                                      \
      pnxt = pptr[(size_t)yn * WW + x];                                      \
    }                                                                        \
    __syncthreads();                                                         \
    v2f hmu = {0.f, 0.f}, hsq = {0.f, 0.f};                                  \
    float htp = 0.f;                                                         \
    _Pragma("unroll")                                                        \
    for (int k = 0; k < 11; ++k) {                                           \
      v2f v = srow[buf][x + k];                                              \
      v2f g2 = {GA_(k), GA_(k)};                                             \
      v2f w = g2 * v;                                                        \
      hmu = hmu + w;                                                         \
      hsq = __builtin_elementwise_fma(w, v, hsq);                            \
      htp = fmaf(w.x, v.y, htp);                                             \
    }                                                                        \
    r_mu[slot] = hmu; r_sq[slot] = hsq; r_tp[slot] = htp;                    \
    if constexpr (jj >= 10) {                                                \
      v2f vmu = {0.f, 0.f}, vsq = {0.f, 0.f};                                \
      float vtp = 0.f;                                                       \
      _Pragma("unroll")                                                      \
      for (int k = 0; k < 11; ++k) {                                         \
        const int s = (jj + 1 + k) % 11;                                     \
        v2f g2 = {GA_(k), GA_(k)};                                           \
        vmu = __builtin_elementwise_fma(g2, r_mu[s], vmu);                   \
        vsq = __builtin_elementwise_fma(g2, r_sq[s], vsq);                   \
        vtp = fmaf(GA_(k), r_tp[s], vtp);                                    \
      }                                                                      \
      float m1 = vmu.x, m2 = vmu.y;                                          \
      float mu11 = m1 * m1, mu22 = m2 * m2, m12 = m1 * m2;                   \
      float s1 = fmaxf(vsq.x - mu11, 1e-6f);                                 \
      float s2 = fmaxf(vsq.y - mu22, 1e-6f);                                 \
      float s12 = vtp - m12;                                                 \
      float root = sqrtf(s1 * s2);                                           \
      float num = fmaf(2.f, m12, C1) * fmaf(2.f, root, C2) * (s12 + C3);     \
      float den = (mu11 + mu22 + C1) * (s1 + s2 + C2) * (root + C3);         \
      acc = fmaf(num, __builtin_amdgcn_rcpf(den), acc);                      \
    }                                                                        \
    tcur = tnxt; pcur = pnxt;                                                \
    __builtin_amdgcn_sched_barrier(0x0007);                                  \
  } while (0)

__global__ __launch_bounds__(256, 6) void k_ssim(const float* __restrict__ pred,
                                                 const float* __restrict__ targ,
                                                 float* __restrict__ wsf,
                                                 float* __restrict__ out) {
  const int img = blockIdx.x >> 4;    // 0..127  (16 chunks/img)
  const int chunk = blockIdx.x & 15;  // 0..15
  const int b = img >> 4;             // sample
  const int x = threadIdx.x;
  const int y0 = chunk * CROWS;
  const float* tptr = targ + (size_t)img * (HH * WW);
  const float* pptr = pred + (size_t)img * (HH * WW);

  // Preamble: reduce this sample's 64 partials -> norm params + valid (wave 0)
  __shared__ float sprm[5];  // ps, pb, ts, tb, valid
  if (x < 64) {
    float mnp = wsf[P_MINP + b * 64 + x];
    float mxp = wsf[P_MAXP + b * 64 + x];
    float mnt = wsf[P_MINT + b * 64 + x];
    float mxt = wsf[P_MAXT + b * 64 + x];
    float st  = wsf[P_SUMT + b * 64 + x];
    for (int off = 32; off > 0; off >>= 1) {
      mnp = fminf(mnp, __shfl_down(mnp, off));
      mxp = fmaxf(mxp, __shfl_down(mxp, off));
      mnt = fminf(mnt, __shfl_down(mnt, off));
      mxt = fmaxf(mxt, __shfl_down(mxt, off));
      st += __shfl_down(st, off);
    }
    if (x == 0) {
      float psv = 1.f / fmaxf(mxp - mnp, 1e-6f);
      float tsv = 1.f / fmaxf(mxt - mnt, 1e-6f);
      sprm[0] = psv; sprm[1] = -mnp * psv;
      sprm[2] = tsv; sprm[3] = -mnt * tsv;
      sprm[4] = (st != 0.f) ? 1.f : 0.f;
    }
  }

  // Double-buffered staging rows of (t,p) float2, 5-wide zero halos.
  __shared__ v2f srow[2][WW + 12];
  if (x < 5) {
    v2f z = {0.f, 0.f};
    srow[0][x] = z; srow[1][x] = z;
    srow[0][WW + 5 + x] = z; srow[1][WW + 5 + x] = z;
  }
  __syncthreads();
  const float ps = sprm[0], pb = sprm[1], ts = sprm[2], tb = sprm[3];

  // Ring: h-conv results for 11 rows; constant indices -> registers.
  v2f r_mu[11], r_sq[11];
  float r_tp[11];
  float acc = 0.f;
  const int ystart = y0 - 5;  // step j stages row ystart+j; output yo = row-5
  const float C1 = 1e-4f, C2 = 9e-4f, C3 = 4.5e-4f;

  // Prime the 1-step prefetch
  float tcur, pcur, tnxt = 0.f, pnxt = 0.f;
  {
    const int yc = min(max(ystart, 0), HH - 1);
    tcur = tptr[(size_t)yc * WW + x];
    pcur = pptr[(size_t)yc * WW + x];
  }

  STEP(0);  STEP(1);  STEP(2);  STEP(3);  STEP(4);  STEP(5);  STEP(6);
  STEP(7);  STEP(8);  STEP(9);  STEP(10); STEP(11); STEP(12); STEP(13);
  STEP(14); STEP(15); STEP(16); STEP(17); STEP(18); STEP(19); STEP(20);
  STEP(21); STEP(22); STEP(23); STEP(24); STEP(25);

  // Block reduction + valid-weighted accumulate + last-block loss finalize
  for (int off = 32; off > 0; off >>= 1) acc += __shfl_down(acc, off);
  __shared__ float sred[4];
  __shared__ bool sdone;
  if ((x & 63) == 0) sred[x >> 6] = acc;
  __syncthreads();
  if (x == 0) {
    float v = sred[0] + sred[1] + sred[2] + sred[3];
    atomicAdd(&wsf[WS_S], v * sprm[4]);
    __threadfence();  // make WS_S add visible before counter bump
    unsigned n = atomicAdd(&((unsigned*)wsf)[WS_CNT], 1u);
    sdone = (n == NBLK - 1);
  }
  __syncthreads();
  if (sdone) {
    // Last block: compute final loss (former k_loss).
    __threadfence();
    float sums[8];
    if (x < 64) {
#pragma unroll
      for (int sb = 0; sb < 8; ++sb) sums[sb] = wsf[P_SUMT + sb * 64 + x];
      for (int off = 32; off > 0; off >>= 1) {
#pragma unroll
        for (int sb = 0; sb < 8; ++sb) sums[sb] += __shfl_down(sums[sb], off);
      }
    }
    if (x == 0) {
      float sv = 0.f;
#pragma unroll
      for (int sb = 0; sb < 8; ++sb) sv += (sums[sb] != 0.f) ? 1.f : 0.f;
      float S = atomicAdd(&wsf[WS_S], 0.f);  // coherent read
      out[0] = (sv - S * (1.f / (float)NPX)) / fmaxf(sv, 1.f);
    }
  }
}

extern "C" void kernel_launch(void* const* d_in, const int* in_sizes, int n_in,
                              void* d_out, int out_size, void* d_ws, size_t ws_size,
                              hipStream_t stream) {
  const float* pred = (const float*)d_in[0];
  const float* targ = (const float*)d_in[1];
  float* wsf = (float*)d_ws;
  float* out = (float*)d_out;

  hipLaunchKernelGGL(k_reduce, dim3(512), dim3(256), 0, stream, pred, targ, wsf);
  hipLaunchKernelGGL(k_ssim, dim3(NBLK), dim3(256), 0, stream, pred, targ, wsf, out);
}

// Round 6
// 175.121 us; speedup vs baseline: 1.3568x; 1.3568x over previous
//
#include <hip/hip_runtime.h>
#include <math.h>

// predicted/target: (B,T,H,W,1) fp32
#define BB 8
#define TT 16
#define HH 256
#define WW 256
#define NPX (TT * HH * WW)      // 1,048,576 px per sample
#define CROWS 16                // output rows per ssim block
#define NSTEP (CROWS + 10)      // staged rows per block = 26
#define NBLK (BB * TT * (HH / CROWS)) // 2048 ssim blocks

// ws float layout (per-block partials from k_reduce; 512 = 8 samples x 64 chunks)
#define P_MINP 0
#define P_MAXP 512
#define P_MINT 1024
#define P_MAXT 1536
#define P_SUMT 2048
#define WS_S   2560   // accumulated valid-weighted ssim sum
#define WS_CNT 2561   // done-block counter (uint)

typedef float v2f __attribute__((ext_vector_type(2)));

// Gaussian taps (exp(-(i-5)^2/4.5), normalized) as literals.
#define G0 0.0010283776f
#define G1 0.0075987582f
#define G2 0.0360008014f
#define G3 0.1093606427f
#define G4 0.2130055745f
#define G5 0.2660117857f
#define GA_(k) ((k) == 0 || (k) == 10 ? G0 : (k) == 1 || (k) == 9 ? G1 \
              : (k) == 2 || (k) == 8 ? G2 : (k) == 3 || (k) == 7 ? G3 \
              : (k) == 4 || (k) == 6 ? G4 : G5)

// Per-sample min/max of pred & targ + sum(targ), one partial per block.
__global__ __launch_bounds__(256) void k_reduce(const float* __restrict__ p,
                                                const float* __restrict__ t,
                                                float* __restrict__ wsf) {
  const int b = blockIdx.x >> 6;
  const size_t base = (size_t)b * NPX + (size_t)(blockIdx.x & 63) * (NPX / 64);
  const int tid = threadIdx.x;

  float mnp = 3.4e38f, mxp = -3.4e38f, mnt = 3.4e38f, mxt = -3.4e38f, st = 0.f;
  const float4* p4 = (const float4*)(p + base);
  const float4* t4 = (const float4*)(t + base);
#pragma unroll 4
  for (int it = 0; it < 16; ++it) {
    float4 a = p4[it * 256 + tid];
    float4 c = t4[it * 256 + tid];
    mnp = fminf(mnp, fminf(fminf(a.x, a.y), fminf(a.z, a.w)));
    mxp = fmaxf(mxp, fmaxf(fmaxf(a.x, a.y), fmaxf(a.z, a.w)));
    mnt = fminf(mnt, fminf(fminf(c.x, c.y), fminf(c.z, c.w)));
    mxt = fmaxf(mxt, fmaxf(fmaxf(c.x, c.y), fmaxf(c.z, c.w)));
    st += c.x + c.y + c.z + c.w;
  }
  for (int off = 32; off > 0; off >>= 1) {
    mnp = fminf(mnp, __shfl_down(mnp, off));
    mxp = fmaxf(mxp, __shfl_down(mxp, off));
    mnt = fminf(mnt, __shfl_down(mnt, off));
    mxt = fmaxf(mxt, __shfl_down(mxt, off));
    st += __shfl_down(st, off);
  }
  __shared__ float s_mnp[4], s_mxp[4], s_mnt[4], s_mxt[4], s_st[4];
  int wave = tid >> 6, lane = tid & 63;
  if (lane == 0) {
    s_mnp[wave] = mnp; s_mxp[wave] = mxp;
    s_mnt[wave] = mnt; s_mxt[wave] = mxt; s_st[wave] = st;
  }
  __syncthreads();
  if (tid == 0) {
    for (int w = 1; w < 4; ++w) {
      mnp = fminf(mnp, s_mnp[w]); mxp = fmaxf(mxp, s_mxp[w]);
      mnt = fminf(mnt, s_mnt[w]); mxt = fmaxf(mxt, s_mxt[w]);
      st += s_st[w];
    }
    wsf[P_MINP + blockIdx.x] = mnp;
    wsf[P_MAXP + blockIdx.x] = mxp;
    wsf[P_MINT + blockIdx.x] = mnt;
    wsf[P_MAXT + blockIdx.x] = mxt;
    wsf[P_SUMT + blockIdx.x] = st;
    if (blockIdx.x == 0) {
      wsf[WS_S] = 0.f;
      ((unsigned*)wsf)[WS_CNT] = 0u;
    }
  }
}

// One row-step of the fused separable SSIM pipeline. jj literal -> buffer
// parity, ring slot, output guard all compile-time; ring arrays see only
// constant indices -> stay in VGPRs. sched_barrier(0) per step: proven (r4)
// to keep the scheduler from hoisting loads / blowing registers.
// NOTE (r5 lesson): do NOT tighten __launch_bounds__ below natural pressure —
// (256,6) forced VGPR cap < 48 and respawned a 152 MB scratch spill.
#define STEP(J) do {                                                         \
    constexpr int jj = (J);                                                  \
    constexpr int buf = jj & 1;                                              \
    constexpr int slot = jj % 11;                                            \
    const bool in = (unsigned)(ystart + jj) < (unsigned)HH;                  \
    v2f nv;                                                                  \
    nv.x = in ? fmaf(tcur, ts, tb) : 0.f;                                    \
    nv.y = in ? fmaf(pcur, ps, pb) : 0.f;                                    \
    srow[buf][x + 5] = nv;                                                   \
    if constexpr (jj < NSTEP - 1) {                                          \
      const int yn = min(max(ystart + jj + 1, 0), HH - 1);                   \
      tnxt = tptr[(size_t)yn * WW + x];                                      \
      pnxt = pptr[(size_t)yn * WW + x];                                      \
    }                                                                        \
    __syncthreads();                                                         \
    v2f hmu = {0.f, 0.f}, hsq = {0.f, 0.f};                                  \
    float htp = 0.f;                                                         \
    _Pragma("unroll")                                                        \
    for (int k = 0; k < 11; ++k) {                                           \
      v2f v = srow[buf][x + k];                                              \
      v2f g2 = {GA_(k), GA_(k)};                                             \
      v2f w = g2 * v;                                                        \
      hmu = hmu + w;                                                         \
      hsq = __builtin_elementwise_fma(w, v, hsq);                            \
      htp = fmaf(w.x, v.y, htp);                                             \
    }                                                                        \
    r_mu[slot] = hmu; r_sq[slot] = hsq; r_tp[slot] = htp;                    \
    if constexpr (jj >= 10) {                                                \
      v2f vmu = {0.f, 0.f}, vsq = {0.f, 0.f};                                \
      float vtp = 0.f;                                                       \
      _Pragma("unroll")                                                      \
      for (int k = 0; k < 11; ++k) {                                         \
        const int s = (jj + 1 + k) % 11;                                     \
        v2f g2 = {GA_(k), GA_(k)};                                           \
        vmu = __builtin_elementwise_fma(g2, r_mu[s], vmu);                   \
        vsq = __builtin_elementwise_fma(g2, r_sq[s], vsq);                   \
        vtp = fmaf(GA_(k), r_tp[s], vtp);                                    \
      }                                                                      \
      float m1 = vmu.x, m2 = vmu.y;                                          \
      float mu11 = m1 * m1, mu22 = m2 * m2, m12 = m1 * m2;                   \
      float s1 = fmaxf(vsq.x - mu11, 1e-6f);                                 \
      float s2 = fmaxf(vsq.y - mu22, 1e-6f);                                 \
      float s12 = vtp - m12;                                                 \
      float root = sqrtf(s1 * s2);                                           \
      float num = fmaf(2.f, m12, C1) * fmaf(2.f, root, C2) * (s12 + C3);     \
      float den = (mu11 + mu22 + C1) * (s1 + s2 + C2) * (root + C3);         \
      acc = fmaf(num, __builtin_amdgcn_rcpf(den), acc);                      \
    }                                                                        \
    tcur = tnxt; pcur = pnxt;                                                \
    __builtin_amdgcn_sched_barrier(0);                                       \
  } while (0)

__global__ __launch_bounds__(256, 3) void k_ssim(const float* __restrict__ pred,
                                                 const float* __restrict__ targ,
                                                 float* __restrict__ wsf,
                                                 float* __restrict__ out) {
  const int img = blockIdx.x >> 4;    // 0..127  (16 chunks/img)
  const int chunk = blockIdx.x & 15;  // 0..15
  const int b = img >> 4;             // sample
  const int x = threadIdx.x;
  const int y0 = chunk * CROWS;
  const float* tptr = targ + (size_t)img * (HH * WW);
  const float* pptr = pred + (size_t)img * (HH * WW);

  // Preamble: reduce this sample's 64 partials -> norm params + valid (wave 0)
  __shared__ float sprm[5];  // ps, pb, ts, tb, valid
  if (x < 64) {
    float mnp = wsf[P_MINP + b * 64 + x];
    float mxp = wsf[P_MAXP + b * 64 + x];
    float mnt = wsf[P_MINT + b * 64 + x];
    float mxt = wsf[P_MAXT + b * 64 + x];
    float st  = wsf[P_SUMT + b * 64 + x];
    for (int off = 32; off > 0; off >>= 1) {
      mnp = fminf(mnp, __shfl_down(mnp, off));
      mxp = fmaxf(mxp, __shfl_down(mxp, off));
      mnt = fminf(mnt, __shfl_down(mnt, off));
      mxt = fmaxf(mxt, __shfl_down(mxt, off));
      st += __shfl_down(st, off);
    }
    if (x == 0) {
      float psv = 1.f / fmaxf(mxp - mnp, 1e-6f);
      float tsv = 1.f / fmaxf(mxt - mnt, 1e-6f);
      sprm[0] = psv; sprm[1] = -mnp * psv;
      sprm[2] = tsv; sprm[3] = -mnt * tsv;
      sprm[4] = (st != 0.f) ? 1.f : 0.f;
    }
  }

  // Double-buffered staging rows of (t,p) float2, 5-wide zero halos.
  __shared__ v2f srow[2][WW + 12];
  if (x < 5) {
    v2f z = {0.f, 0.f};
    srow[0][x] = z; srow[1][x] = z;
    srow[0][WW + 5 + x] = z; srow[1][WW + 5 + x] = z;
  }
  __syncthreads();
  const float ps = sprm[0], pb = sprm[1], ts = sprm[2], tb = sprm[3];

  // Ring: h-conv results for 11 rows; constant indices -> registers.
  v2f r_mu[11], r_sq[11];
  float r_tp[11];
  float acc = 0.f;
  const int ystart = y0 - 5;  // step j stages row ystart+j; output yo = row-5
  const float C1 = 1e-4f, C2 = 9e-4f, C3 = 4.5e-4f;

  // Prime the 1-step prefetch
  float tcur, pcur, tnxt = 0.f, pnxt = 0.f;
  {
    const int yc = min(max(ystart, 0), HH - 1);
    tcur = tptr[(size_t)yc * WW + x];
    pcur = pptr[(size_t)yc * WW + x];
  }

  STEP(0);  STEP(1);  STEP(2);  STEP(3);  STEP(4);  STEP(5);  STEP(6);
  STEP(7);  STEP(8);  STEP(9);  STEP(10); STEP(11); STEP(12); STEP(13);
  STEP(14); STEP(15); STEP(16); STEP(17); STEP(18); STEP(19); STEP(20);
  STEP(21); STEP(22); STEP(23); STEP(24); STEP(25);

  // Block reduction + valid-weighted accumulate + last-block loss finalize
  for (int off = 32; off > 0; off >>= 1) acc += __shfl_down(acc, off);
  __shared__ float sred[4];
  __shared__ bool sdone;
  if ((x & 63) == 0) sred[x >> 6] = acc;
  __syncthreads();
  if (x == 0) {
    float v = sred[0] + sred[1] + sred[2] + sred[3];
    atomicAdd(&wsf[WS_S], v * sprm[4]);
    __threadfence();  // make WS_S add visible before counter bump
    unsigned n = atomicAdd(&((unsigned*)wsf)[WS_CNT], 1u);
    sdone = (n == NBLK - 1);
  }
  __syncthreads();
  if (sdone) {
    // Last block: compute final loss (former k_loss).
    __threadfence();
    float sums[8];
    if (x < 64) {
#pragma unroll
      for (int sb = 0; sb < 8; ++sb) sums[sb] = wsf[P_SUMT + sb * 64 + x];
      for (int off = 32; off > 0; off >>= 1) {
#pragma unroll
        for (int sb = 0; sb < 8; ++sb) sums[sb] += __shfl_down(sums[sb], off);
      }
    }
    if (x == 0) {
      float sv = 0.f;
#pragma unroll
      for (int sb = 0; sb < 8; ++sb) sv += (sums[sb] != 0.f) ? 1.f : 0.f;
      float S = atomicAdd(&wsf[WS_S], 0.f);  // coherent read
      out[0] = (sv - S * (1.f / (float)NPX)) / fmaxf(sv, 1.f);
    }
  }
}

extern "C" void kernel_launch(void* const* d_in, const int* in_sizes, int n_in,
                              void* d_out, int out_size, void* d_ws, size_t ws_size,
                              hipStream_t stream) {
  const float* pred = (const float*)d_in[0];
  const float* targ = (const float*)d_in[1];
  float* wsf = (float*)d_ws;
  float* out = (float*)d_out;

  hipLaunchKernelGGL(k_reduce, dim3(512), dim3(256), 0, stream, pred, targ, wsf);
  hipLaunchKernelGGL(k_ssim, dim3(NBLK), dim3(256), 0, stream, pred, targ, wsf, out);
}

// Round 7
// 134.074 us; speedup vs baseline: 1.7722x; 1.3062x over previous
//
#include <hip/hip_runtime.h>
#include <math.h>

// predicted/target: (B,T,H,W,1) fp32
#define BB 8
#define TT 16
#define HH 256
#define WW 256
#define NPX (TT * HH * WW)      // 1,048,576 px per sample
#define CROWS 32                // output rows per ssim block
#define NROWS (CROWS + 10)      // 42 staged rows per block
#define NSLOT 8                 // LDS row-ring slots (power of 2, >= 4+4)
#define NBLK (BB * TT * (HH / CROWS)) // 1024 ssim blocks

// ws float layout (per-block partials from k_reduce; 512 = 8 samples x 64 chunks)
#define P_MINP 0
#define P_MAXP 512
#define P_MINT 1024
#define P_MAXT 1536
#define P_SUMT 2048
#define WS_S   2560   // accumulated valid-weighted ssim sum

typedef float v2f __attribute__((ext_vector_type(2)));

// Gaussian taps (exp(-(i-5)^2/4.5), normalized) as literals.
#define G0 0.0010283776f
#define G1 0.0075987582f
#define G2 0.0360008014f
#define G3 0.1093606427f
#define G4 0.2130055745f
#define G5 0.2660117857f
#define GA_(k) ((k) == 0 || (k) == 10 ? G0 : (k) == 1 || (k) == 9 ? G1 \
              : (k) == 2 || (k) == 8 ? G2 : (k) == 3 || (k) == 7 ? G3 \
              : (k) == 4 || (k) == 6 ? G4 : G5)

// Per-sample min/max of pred & targ + sum(targ), one partial per block.
__global__ __launch_bounds__(256) void k_reduce(const float* __restrict__ p,
                                                const float* __restrict__ t,
                                                float* __restrict__ wsf) {
  const int b = blockIdx.x >> 6;
  const size_t base = (size_t)b * NPX + (size_t)(blockIdx.x & 63) * (NPX / 64);
  const int tid = threadIdx.x;

  float mnp = 3.4e38f, mxp = -3.4e38f, mnt = 3.4e38f, mxt = -3.4e38f, st = 0.f;
  const float4* p4 = (const float4*)(p + base);
  const float4* t4 = (const float4*)(t + base);
#pragma unroll 4
  for (int it = 0; it < 16; ++it) {
    float4 a = p4[it * 256 + tid];
    float4 c = t4[it * 256 + tid];
    mnp = fminf(mnp, fminf(fminf(a.x, a.y), fminf(a.z, a.w)));
    mxp = fmaxf(mxp, fmaxf(fmaxf(a.x, a.y), fmaxf(a.z, a.w)));
    mnt = fminf(mnt, fminf(fminf(c.x, c.y), fminf(c.z, c.w)));
    mxt = fmaxf(mxt, fmaxf(fmaxf(c.x, c.y), fmaxf(c.z, c.w)));
    st += c.x + c.y + c.z + c.w;
  }
  for (int off = 32; off > 0; off >>= 1) {
    mnp = fminf(mnp, __shfl_down(mnp, off));
    mxp = fmaxf(mxp, __shfl_down(mxp, off));
    mnt = fminf(mnt, __shfl_down(mnt, off));
    mxt = fmaxf(mxt, __shfl_down(mxt, off));
    st += __shfl_down(st, off);
  }
  __shared__ float s_mnp[4], s_mxp[4], s_mnt[4], s_mxt[4], s_st[4];
  int wave = tid >> 6, lane = tid & 63;
  if (lane == 0) {
    s_mnp[wave] = mnp; s_mxp[wave] = mxp;
    s_mnt[wave] = mnt; s_mxt[wave] = mxt; s_st[wave] = st;
  }
  __syncthreads();
  if (tid == 0) {
    for (int w = 1; w < 4; ++w) {
      mnp = fminf(mnp, s_mnp[w]); mxp = fmaxf(mxp, s_mxp[w]);
      mnt = fminf(mnt, s_mnt[w]); mxt = fmaxf(mxt, s_mxt[w]);
      st += s_st[w];
    }
    wsf[P_MINP + blockIdx.x] = mnp;
    wsf[P_MAXP + blockIdx.x] = mxp;
    wsf[P_MINT + blockIdx.x] = mnt;
    wsf[P_MAXT + blockIdx.x] = mxt;
    wsf[P_SUMT + blockIdx.x] = st;
    if (blockIdx.x == 0) wsf[WS_S] = 0.f;
  }
}

// --- Phase-grouped pipeline macros. All row indices are literals so the
// register ring (%11) and LDS slot (&7) are compile-time. One barrier per
// 4-row phase: loads for rows r+4..r+7 issue at phase start, have the 4-row
// compute (~1k cyc) to land, then the (compiler-emitted) vmcnt drain before
// s_barrier is nearly free — this removes the r4/r6 per-row drain serial.

#define LOADR(R) do { constexpr int r_ = (R); if constexpr (r_ < NROWS) {     \
    const int yc_ = min(max(ystart + r_, 0), HH - 1);                          \
    tpre[r_ & 3] = tptr[(size_t)yc_ * WW + x];                                 \
    ppre[r_ & 3] = pptr[(size_t)yc_ * WW + x];                                 \
  } } while (0)

#define WRITER(R) do { constexpr int r_ = (R); if constexpr (r_ < NROWS) {     \
    const bool in_ = (unsigned)(ystart + r_) < (unsigned)HH;                   \
    v2f nv_;                                                                   \
    nv_.x = in_ ? fmaf(tpre[r_ & 3], ts, tb) : 0.f;                            \
    nv_.y = in_ ? fmaf(ppre[r_ & 3], ps, pb) : 0.f;                            \
    srow[r_ & (NSLOT - 1)][x + 5] = nv_;                                       \
  } } while (0)

#define CSTEP(R) do { constexpr int r_ = (R); if constexpr (r_ < NROWS) {      \
    constexpr int slot_ = r_ % 11;                                             \
    v2f hmu = {0.f, 0.f}, hsq = {0.f, 0.f};                                    \
    float htp = 0.f;                                                           \
    _Pragma("unroll")                                                          \
    for (int k = 0; k < 11; ++k) {                                             \
      v2f v = srow[r_ & (NSLOT - 1)][x + k];                                   \
      v2f g2 = {GA_(k), GA_(k)};                                               \
      v2f w = g2 * v;                                                          \
      hmu = hmu + w;                                                           \
      hsq = __builtin_elementwise_fma(w, v, hsq);                              \
      htp = fmaf(w.x, v.y, htp);                                               \
    }                                                                          \
    r_mu[slot_] = hmu; r_sq[slot_] = hsq; r_tp[slot_] = htp;                   \
    if constexpr (r_ >= 10) {                                                  \
      v2f vmu = {0.f, 0.f}, vsq = {0.f, 0.f};                                  \
      float vtp = 0.f;                                                         \
      _Pragma("unroll")                                                        \
      for (int k = 0; k < 11; ++k) {                                           \
        const int s = (r_ + 1 + k) % 11;                                       \
        v2f g2 = {GA_(k), GA_(k)};                                             \
        vmu = __builtin_elementwise_fma(g2, r_mu[s], vmu);                     \
        vsq = __builtin_elementwise_fma(g2, r_sq[s], vsq);                     \
        vtp = fmaf(GA_(k), r_tp[s], vtp);                                      \
      }                                                                        \
      float m1 = vmu.x, m2 = vmu.y;                                            \
      float mu11 = m1 * m1, mu22 = m2 * m2, m12 = m1 * m2;                     \
      float s1 = fmaxf(vsq.x - mu11, 1e-6f);                                   \
      float s2 = fmaxf(vsq.y - mu22, 1e-6f);                                   \
      float s12 = vtp - m12;                                                   \
      float root = sqrtf(s1 * s2);                                             \
      float num = fmaf(2.f, m12, C1) * fmaf(2.f, root, C2) * (s12 + C3);       \
      float den = (mu11 + mu22 + C1) * (s1 + s2 + C2) * (root + C3);           \
      acc = fmaf(num, __builtin_amdgcn_rcpf(den), acc);                        \
    }                                                                          \
  } } while (0)

#define PHASE(P) do {                                                          \
    LOADR(4*(P)+4); LOADR(4*(P)+5); LOADR(4*(P)+6); LOADR(4*(P)+7);            \
    CSTEP(4*(P)+0); CSTEP(4*(P)+1); CSTEP(4*(P)+2); CSTEP(4*(P)+3);            \
    WRITER(4*(P)+4); WRITER(4*(P)+5); WRITER(4*(P)+6); WRITER(4*(P)+7);        \
    __syncthreads();                                                           \
    __builtin_amdgcn_sched_barrier(0);                                         \
  } while (0)

__global__ __launch_bounds__(256, 3) void k_ssim(const float* __restrict__ pred,
                                                 const float* __restrict__ targ,
                                                 float* __restrict__ wsf) {
  const int img = blockIdx.x >> 3;    // 0..127  (8 chunks/img)
  const int chunk = blockIdx.x & 7;   // 0..7
  const int b = img >> 4;             // sample
  const int x = threadIdx.x;
  const int y0 = chunk * CROWS;
  const float* tptr = targ + (size_t)img * (HH * WW);
  const float* pptr = pred + (size_t)img * (HH * WW);

  // Preamble: reduce this sample's 64 partials -> norm params + valid (wave 0)
  __shared__ float sprm[5];  // ps, pb, ts, tb, valid
  if (x < 64) {
    float mnp = wsf[P_MINP + b * 64 + x];
    float mxp = wsf[P_MAXP + b * 64 + x];
    float mnt = wsf[P_MINT + b * 64 + x];
    float mxt = wsf[P_MAXT + b * 64 + x];
    float st  = wsf[P_SUMT + b * 64 + x];
    for (int off = 32; off > 0; off >>= 1) {
      mnp = fminf(mnp, __shfl_down(mnp, off));
      mxp = fmaxf(mxp, __shfl_down(mxp, off));
      mnt = fminf(mnt, __shfl_down(mnt, off));
      mxt = fmaxf(mxt, __shfl_down(mxt, off));
      st += __shfl_down(st, off);
    }
    if (x == 0) {
      float psv = 1.f / fmaxf(mxp - mnp, 1e-6f);
      float tsv = 1.f / fmaxf(mxt - mnt, 1e-6f);
      sprm[0] = psv; sprm[1] = -mnp * psv;
      sprm[2] = tsv; sprm[3] = -mnt * tsv;
      sprm[4] = (st != 0.f) ? 1.f : 0.f;
    }
  }

  // LDS row ring: NSLOT rows of (t,p) v2f with 5-wide zero halos each side.
  __shared__ v2f srow[NSLOT][WW + 12];
  if (x < 5) {
    v2f z = {0.f, 0.f};
#pragma unroll
    for (int s = 0; s < NSLOT; ++s) {
      srow[s][x] = z;
      srow[s][WW + 5 + x] = z;
    }
  }
  __syncthreads();
  const float ps = sprm[0], pb = sprm[1], ts = sprm[2], tb = sprm[3];

  // Register ring: h-conv results for 11 rows; constant indices -> VGPRs.
  v2f r_mu[11], r_sq[11];
  float r_tp[11];
  float acc = 0.f;
  const int ystart = y0 - 5;  // staged row r is image row ystart+r
  const float C1 = 1e-4f, C2 = 9e-4f, C3 = 4.5e-4f;

  float tpre[4], ppre[4];

  // Prologue: stage rows 0..3
  LOADR(0); LOADR(1); LOADR(2); LOADR(3);
  WRITER(0); WRITER(1); WRITER(2); WRITER(3);
  __syncthreads();
  __builtin_amdgcn_sched_barrier(0);

  PHASE(0); PHASE(1); PHASE(2); PHASE(3); PHASE(4);
  PHASE(5); PHASE(6); PHASE(7); PHASE(8); PHASE(9);
  // Tail rows 40..41 (written during PHASE(9))
  CSTEP(40); CSTEP(41);

  // Block reduction + valid-weighted accumulate
  for (int off = 32; off > 0; off >>= 1) acc += __shfl_down(acc, off);
  __shared__ float sred[4];
  if ((x & 63) == 0) sred[x >> 6] = acc;
  __syncthreads();
  if (x == 0) {
    float v = sred[0] + sred[1] + sred[2] + sred[3];
    atomicAdd(&wsf[WS_S], v * sprm[4]);
  }
}

__global__ void k_loss(const float* __restrict__ wsf, float* __restrict__ out) {
  const int c = threadIdx.x;  // 64 threads
  float sums[8];
#pragma unroll
  for (int b = 0; b < 8; ++b) sums[b] = wsf[P_SUMT + b * 64 + c];
  for (int off = 32; off > 0; off >>= 1) {
#pragma unroll
    for (int b = 0; b < 8; ++b) sums[b] += __shfl_down(sums[b], off);
  }
  if (c == 0) {
    float sv = 0.f;
#pragma unroll
    for (int b = 0; b < 8; ++b) sv += (sums[b] != 0.f) ? 1.f : 0.f;
    float S = wsf[WS_S];
    out[0] = (sv - S * (1.f / (float)NPX)) / fmaxf(sv, 1.f);
  }
}

extern "C" void kernel_launch(void* const* d_in, const int* in_sizes, int n_in,
                              void* d_out, int out_size, void* d_ws, size_t ws_size,
                              hipStream_t stream) {
  const float* pred = (const float*)d_in[0];
  const float* targ = (const float*)d_in[1];
  float* wsf = (float*)d_ws;
  float* out = (float*)d_out;

  hipLaunchKernelGGL(k_reduce, dim3(512), dim3(256), 0, stream, pred, targ, wsf);
  hipLaunchKernelGGL(k_ssim, dim3(NBLK), dim3(256), 0, stream, pred, targ, wsf);
  hipLaunchKernelGGL(k_loss, dim3(1), dim3(64), 0, stream, wsf, out);
}